// Round 8
// baseline (125.881 us; speedup 1.0000x reference)
//
#include <hip/hip_runtime.h>
#include <hip/hip_bf16.h>

// Ensemble Q-network, fused, transposed ([features x batch]).
//   h1^T = relu(W1^T x^T + b1);  acc = W2^T h1^T + b2;  out = W3 . relu(acc)  in-register.
// R8 = R4 structure (BT=128, 16x16x32, 2560 blocks x 512 thr, 2 blocks/CU) with the
// epilogue-1 __syncthreads REPLACED by per-slice-pair producer/consumer flags:
// h1 kt-slices {2c,2c+1} are produced solely by the two cg==c waves, so each wave
// K-loops in rotated order starting at its OWN slices (kt = 2cg, 2cg+1, ...) and
// waits only on a 2-wave rendezvous per pair -> no 8-wave convoy, staggered L2/LDS.

typedef __attribute__((ext_vector_type(8))) short bf16x8;   // 8 bf16 (4 VGPRs)
typedef __attribute__((ext_vector_type(4))) float f32x4;    // MFMA C/D

#define B_TOTAL 32768
#define NQ 10
#define HDIM 256
#define BT 128

#define XP_ELEMS  (B_TOTAL * 32)            // bf16 x, k-padded to 32
#define W1P_ELEMS (NQ * 16 * 64 * 8)        // [n][mtile16][lane64][j8]
#define W2P_ELEMS (NQ * 8 * 16 * 64 * 8)    // [n][kt8][mtile16][lane64][j8]

__device__ __forceinline__ unsigned short f2bf(float f) {
  unsigned int u = __float_as_uint(f);
  u = u + 0x7FFFu + ((u >> 16) & 1u);
  return (unsigned short)(u >> 16);
}

__device__ __forceinline__ unsigned int pk2bf(float a, float b) {
  union { __hip_bfloat162 h; unsigned int u; } cv;
  cv.h = __float22bfloat162_rn(make_float2(a, b));
  return cv.u;
}

// ---- single pack dispatch: x, W1^T (16x16 A-order), W2^T (16x16 A-order) ----
__global__ void pack_all_kernel(const float* __restrict__ state,
                                const float* __restrict__ action,
                                const float* __restrict__ W1,
                                const float* __restrict__ W2,
                                unsigned short* __restrict__ xp,
                                unsigned short* __restrict__ w1p,
                                unsigned short* __restrict__ w2p) {
  int t = blockIdx.x * 256 + threadIdx.x;   // 872 * 256 = 223232 exactly
  const int NX  = B_TOTAL * 4;              // 131072 uint4 chunks of xp
  const int NW1 = NQ * 16 * 64;             // 10240
  if (t < NX) {
    int b = t >> 2, seg = t & 3;
    unsigned short v[8];
    if (seg < 2) {
      const float* sp = state + (size_t)b * 17 + seg * 8;
#pragma unroll
      for (int j = 0; j < 8; j++) v[j] = f2bf(sp[j]);
    } else if (seg == 2) {
      v[0] = f2bf(state[(size_t)b * 17 + 16]);
#pragma unroll
      for (int j = 0; j < 6; j++) v[1 + j] = f2bf(action[(size_t)b * 6 + j]);
      v[7] = 0;
    } else {
#pragma unroll
      for (int j = 0; j < 8; j++) v[j] = 0;
    }
    *(uint4*)&xp[(size_t)t * 8] = *(const uint4*)v;
  } else if (t < NX + NW1) {
    int u = t - NX;
    int lane = u & 63, mt = (u >> 6) & 15, n = u >> 10;
    int m = lane & 15, q = lane >> 4;
    int outc = mt * 16 + m;
    unsigned short v[8];
#pragma unroll
    for (int j = 0; j < 8; j++) {
      int k = q * 8 + j;
      v[j] = (k < 23) ? f2bf(W1[(n * 23 + k) * 256 + outc]) : (unsigned short)0;
    }
    *(uint4*)&w1p[(size_t)u * 8] = *(const uint4*)v;
  } else {
    int u = t - NX - NW1;                   // < 81920
    int lane = u & 63, mt = (u >> 6) & 15, kt = (u >> 10) & 7, n = u >> 13;
    int m = lane & 15, q = lane >> 4;
    int outc = mt * 16 + m;
    unsigned short v[8];
#pragma unroll
    for (int j = 0; j < 8; j++) {
      int h = kt * 32 + q * 8 + j;
      v[j] = f2bf(W2[((size_t)(n * 256 + h)) * 256 + outc]);
    }
    *(uint4*)&w2p[(size_t)u * 8] = *(const uint4*)v;
  }
}

// ---- fused MLP: 2560 blocks x 512 threads (8 waves), 2 blocks/CU ----
// wave w: cg = w>>1 (64 channels), colg = w&1 (64 batch cols)
__global__ __launch_bounds__(512, 4) void fused_ensemble_kernel(
    const unsigned short* __restrict__ xp,
    const unsigned short* __restrict__ w1p,
    const float* __restrict__ b1,
    const unsigned short* __restrict__ w2p,
    const float* __restrict__ b2,
    const float* __restrict__ W3,
    const float* __restrict__ b3,
    float* __restrict__ out) {
  __shared__ __align__(16) unsigned short hs[32 * BT * 8];  // 64 KB, [ch/8][col][8]
  __shared__ float red[8 * 64];                             // 2 KB cross-wave reduce
  __shared__ int flg[4];                                    // per-slice-pair flags

  const int tid = threadIdx.x;
  const int lane = tid & 63;
  const int w = tid >> 6;
  const int m = lane & 15;
  const int q = lane >> 4;
  const int cg = w >> 1;        // channels [cg*64, cg*64+64)
  const int colg = w & 1;       // cols [colg*64, colg*64+64)

  const int n = blockIdx.x >> 8;            // 256 tiles per net
  const int row0 = (blockIdx.x & 255) * BT;

  const unsigned short* w2n = w2p + (size_t)n * (8 * 16 * 64 * 8);

  if (tid < 4) flg[tid] = 0;
  __syncthreads();   // flag init visible before any signal (only barrier pre-K-loop)

  // ---- layer 1: 16x16x32, single K-step; wave tile 64ch x 64col (4x4 frags) ----
  f32x4 acc[4][4];
  {
    bf16x8 af[4], bfr[4];
#pragma unroll
    for (int nt = 0; nt < 4; nt++) {
      int col = row0 + colg * 64 + nt * 16 + m;
      bfr[nt] = *(const bf16x8*)(xp + (size_t)col * 32 + q * 8);
    }
#pragma unroll
    for (int mt = 0; mt < 4; mt++)
      af[mt] = *(const bf16x8*)(w1p + (((size_t)n * 16 + cg * 4 + mt) * 64 + lane) * 8);
#pragma unroll
    for (int mt = 0; mt < 4; mt++) {
      float4 bv = *(const float4*)&b1[n * HDIM + (cg * 4 + mt) * 16 + q * 4];
      f32x4 bi = (f32x4){bv.x, bv.y, bv.z, bv.w};
#pragma unroll
      for (int nt = 0; nt < 4; nt++) acc[mt][nt] = bi;
    }
#pragma unroll
    for (int nt = 0; nt < 4; nt++)
#pragma unroll
      for (int mt = 0; mt < 4; mt++)
        acc[mt][nt] = __builtin_amdgcn_mfma_f32_16x16x32_bf16(af[mt], bfr[nt], acc[mt][nt], 0, 0, 0);
  }

  // ---- preload layer-2 A-frags for this wave's FIRST kt (= 2*cg) + bias init ----
  bf16x8 aE[4];
  const int kt0 = 2 * cg;
#pragma unroll
  for (int mt = 0; mt < 4; mt++)
    aE[mt] = *(const bf16x8*)(w2n + (((size_t)kt0 * 16 + cg * 4 + mt) * 64 + lane) * 8);

  f32x4 acc2[4][4];
#pragma unroll
  for (int mt = 0; mt < 4; mt++) {
    float4 bv = *(const float4*)&b2[n * HDIM + (cg * 4 + mt) * 16 + q * 4];
    f32x4 bi = (f32x4){bv.x, bv.y, bv.z, bv.w};
#pragma unroll
    for (int nt = 0; nt < 4; nt++) acc2[mt][nt] = bi;
  }

  // ---- epilogue 1: relu -> h1 bf16, frag-chunk layout [ch/8][col][8] ----
#pragma unroll
  for (int mt = 0; mt < 4; mt++) {
    int kq = cg * 8 + mt * 2 + (q >> 1);
    int joff = (q & 1) * 4;
#pragma unroll
    for (int nt = 0; nt < 4; nt++) {
      int col = colg * 64 + nt * 16 + m;
      f32x4 a = acc[mt][nt];
      uint2 wv;
      wv.x = pk2bf(fmaxf(a[0], 0.f), fmaxf(a[1], 0.f));
      wv.y = pk2bf(fmaxf(a[2], 0.f), fmaxf(a[3], 0.f));
      *(uint2*)&hs[((size_t)kq * BT + col) * 8 + joff] = wv;
    }
  }
  // signal: this wave's slice pair (kt 2cg, 2cg+1) is written
  __threadfence_block();
  if (lane == 0)
    __hip_atomic_fetch_add(&flg[cg], 1, __ATOMIC_RELEASE, __HIP_MEMORY_SCOPE_WORKGROUP);

  // ---- layer 2: 8 K-steps in rotated order (own slices first), flag-gated ----
  {
#pragma unroll
    for (int ii = 0; ii < 4; ii++) {
      const int ktE = (2 * cg + 2 * ii) & 7;       // even member of the pair
      const int pair = ktE >> 1;
      // 2-wave rendezvous: both cg==pair waves must have written this pair
      while (__hip_atomic_load(&flg[pair], __ATOMIC_ACQUIRE, __HIP_MEMORY_SCOPE_WORKGROUP) < 2) {
        __builtin_amdgcn_s_sleep(1);
      }
      // B-frags for even+odd members (LDS), A-frags for odd (L2)
      bf16x8 bE[4], bO[4], aO[4];
#pragma unroll
      for (int nt = 0; nt < 4; nt++)
        bE[nt] = *(const bf16x8*)&hs[(((size_t)ktE * 4 + q) * BT + colg * 64 + nt * 16 + m) * 8];
#pragma unroll
      for (int nt = 0; nt < 4; nt++)
        bO[nt] = *(const bf16x8*)&hs[(((size_t)(ktE + 1) * 4 + q) * BT + colg * 64 + nt * 16 + m) * 8];
#pragma unroll
      for (int mt = 0; mt < 4; mt++)
        aO[mt] = *(const bf16x8*)(w2n + (((size_t)(ktE + 1) * 16 + cg * 4 + mt) * 64 + lane) * 8);
      // even MFMAs
#pragma unroll
      for (int nt = 0; nt < 4; nt++)
#pragma unroll
        for (int mt = 0; mt < 4; mt++)
          acc2[mt][nt] = __builtin_amdgcn_mfma_f32_16x16x32_bf16(aE[mt], bE[nt], acc2[mt][nt], 0, 0, 0);
      // prefetch next pair's even A-frags (L2) under the odd MFMAs
      if (ii < 3) {
        const int ktN = (ktE + 2) & 7;
#pragma unroll
        for (int mt = 0; mt < 4; mt++)
          aE[mt] = *(const bf16x8*)(w2n + (((size_t)ktN * 16 + cg * 4 + mt) * 64 + lane) * 8);
      }
      // odd MFMAs
#pragma unroll
      for (int nt = 0; nt < 4; nt++)
#pragma unroll
        for (int mt = 0; mt < 4; mt++)
          acc2[mt][nt] = __builtin_amdgcn_mfma_f32_16x16x32_bf16(aO[mt], bO[nt], acc2[mt][nt], 0, 0, 0);
    }
  }

  // ---- layer 3 in-register: p[col] = sum_ch relu(acc2_ch) * W3[ch]; reduce ----
  {
    float4 w3v[4];
#pragma unroll
    for (int mt = 0; mt < 4; mt++)
      w3v[mt] = *(const float4*)&W3[n * HDIM + (cg * 4 + mt) * 16 + q * 4];
    float p[4];
#pragma unroll
    for (int nt = 0; nt < 4; nt++) {
      float s = 0.f;
#pragma unroll
      for (int mt = 0; mt < 4; mt++) {
        f32x4 a = acc2[mt][nt];
        float4 wv = w3v[mt];
        s = fmaf(fmaxf(a[0], 0.f), wv.x, s);
        s = fmaf(fmaxf(a[1], 0.f), wv.y, s);
        s = fmaf(fmaxf(a[2], 0.f), wv.z, s);
        s = fmaf(fmaxf(a[3], 0.f), wv.w, s);
      }
      s += __shfl_xor(s, 16, 64);   // reduce q within wave (channels)
      s += __shfl_xor(s, 32, 64);
      p[nt] = s;
    }
    if (q == 0) {
#pragma unroll
      for (int nt = 0; nt < 4; nt++) red[w * 64 + nt * 16 + m] = p[nt];
    }
    __syncthreads();
    if (tid < BT) {
      int g = tid >> 6, lc = tid & 63;       // col group, local col
      float s = b3[n];
#pragma unroll
      for (int c = 0; c < 4; c++) s += red[(c * 2 + g) * 64 + lc];
      out[(size_t)n * B_TOTAL + row0 + tid] = s;
    }
  }
}

extern "C" void kernel_launch(void* const* d_in, const int* in_sizes, int n_in,
                              void* d_out, int out_size, void* d_ws, size_t ws_size,
                              hipStream_t stream) {
  const float* state  = (const float*)d_in[0];
  const float* action = (const float*)d_in[1];
  const float* W1 = (const float*)d_in[2];
  const float* b1 = (const float*)d_in[3];
  const float* W2 = (const float*)d_in[4];
  const float* b2 = (const float*)d_in[5];
  const float* W3 = (const float*)d_in[6];
  const float* b3 = (const float*)d_in[7];
  float* out = (float*)d_out;

  unsigned short* xp  = (unsigned short*)d_ws;                                    // 2,097,152 B
  unsigned short* w1p = (unsigned short*)((char*)d_ws + (size_t)XP_ELEMS * 2);    //   163,840 B
  unsigned short* w2p = (unsigned short*)((char*)d_ws + (size_t)(XP_ELEMS + W1P_ELEMS) * 2); // 1,310,720 B

  pack_all_kernel<<<872, 256, 0, stream>>>(state, action, W1, W2, xp, w1p, w2p);
  fused_ensemble_kernel<<<NQ * (B_TOTAL / BT), 512, 0, stream>>>(
      xp, w1p, b1, w2p, b2, W3, b3, out);
}